// Round 6
// baseline (280.170 us; speedup 1.0000x reference)
//
#include <hip/hip_runtime.h>
#include <stdint.h>

// R6: R5 + (a) swapped-operand GEMM epilogue (vectorized 8B C-stores via
// cvt_pk), (b) Q2+KV2 fused into one dispatch, (c) single fused cvt kernel.
// attn4 byte-identical to R5 (verified). B=4 S=1024 D=1024 H=16 DK=64.

typedef unsigned short u16;
typedef short b16x8 __attribute__((ext_vector_type(8)));
typedef short b16x4 __attribute__((ext_vector_type(4)));
typedef float f32x4 __attribute__((ext_vector_type(4)));

__device__ __forceinline__ u16 f2bf(float f) {
  union { float f; uint32_t u; } v; v.f = f;
  uint32_t r = v.u + 0x7fffu + ((v.u >> 16) & 1u);
  return (u16)(r >> 16);
}

__device__ __forceinline__ f32x4 mfma16(b16x8 a, b16x8 b, f32x4 c) {
  return __builtin_amdgcn_mfma_f32_16x16x32_bf16(a, b, c, 0, 0, 0);
}

__device__ __forceinline__ void gld16(const void* g, void* l) {
  __builtin_amdgcn_global_load_lds(
      (const __attribute__((address_space(1))) void*)g,
      (__attribute__((address_space(3))) void*)l, 16, 0, 0);
}

__device__ __forceinline__ float ex2(float x) {
  float r; asm("v_exp_f32 %0, %1" : "=v"(r) : "v"(x)); return r;
}

__device__ __forceinline__ uint32_t cvtpk(float a, float b) {
  uint32_t r;
  asm("v_cvt_pk_bf16_f32 %0, %1, %2" : "=v"(r) : "v"(a), "v"(b));
  return r;
}

// ---------------- fused f32 -> bf16 convert (x, enc, 6 weights) ----------
// blocks: [0,2048) x ; [2048,4096) enc ; [4096,7168) weights (512 each).
__global__ __launch_bounds__(256) void k_cvt_all(
    const float* __restrict__ x, const float* __restrict__ enc,
    const float* __restrict__ w0, const float* __restrict__ w1,
    const float* __restrict__ w2, const float* __restrict__ w3,
    const float* __restrict__ w4, const float* __restrict__ w5,
    u16* __restrict__ xb, u16* __restrict__ encb,
    u16* __restrict__ wsc, u16* __restrict__ wcc) {
  const int id = blockIdx.x;
  const float* in;
  u16* out;
  float sc = 1.0f;
  int off;
  if (id < 2048) {
    in = x; out = xb; off = id;
  } else if (id < 4096) {
    in = enc; out = encb; off = id - 2048;
  } else {
    const int wi = (id - 4096) >> 9;
    off = (id - 4096) & 511;
    switch (wi) {
      case 0: in = w0; break; case 1: in = w1; break; case 2: in = w2; break;
      case 3: in = w3; break; case 4: in = w4; break; default: in = w5; break;
    }
    out = (wi < 3 ? wsc : wcc) + (wi % 3) * 1048576;
    if (wi % 3 == 0) sc = 0.18033688f;  // 0.125 * log2(e) folded into wq
  }
  const int i = (off * 256 + threadIdx.x) * 8;
  float4 a = *(const float4*)(in + i);
  float4 b = *(const float4*)(in + i + 4);
  b16x8 v;
  v[0] = (short)f2bf(a.x * sc); v[1] = (short)f2bf(a.y * sc);
  v[2] = (short)f2bf(a.z * sc); v[3] = (short)f2bf(a.w * sc);
  v[4] = (short)f2bf(b.x * sc); v[5] = (short)f2bf(b.y * sc);
  v[6] = (short)f2bf(b.z * sc); v[7] = (short)f2bf(b.w * sc);
  *(b16x8*)(out + i) = v;
}

// ---------------- bf16 GEMM: C[M,N] = A[M,K].B[N,K]^T, dual problem mux ---
// 128x128 tile, BK=32, M=4096, K=1024 fixed. bx < nbx0 -> set0, else set1.
// Swapped-operand MFMA: D rows = B(N), cols = A(M) -> 8B vectorized C-store.
__global__ __launch_bounds__(256) void k_gemm_bt(
    const u16* __restrict__ A0, const u16* __restrict__ B0,
    u16* __restrict__ C0, int N0, int nbx0,
    const u16* __restrict__ A1, const u16* __restrict__ B1,
    u16* __restrict__ C1, int N1) {
  __shared__ u16 Ab[128 * 32];
  __shared__ u16 Bb[128 * 32];
  const int tid = threadIdx.x;
  const int lane = tid & 63, w = tid >> 6;
  const int wr = w >> 1, wc = w & 1;
  const int q = lane & 15, hi = lane >> 4;
  const int nwg = gridDim.x * gridDim.y;
  const int id = blockIdx.y * gridDim.x + blockIdx.x;
  const int swz = (id & 7) * (nwg >> 3) + (id >> 3);  // bijective (nwg%8==0)
  const int bx = swz % gridDim.x, by = swz / gridDim.x;
  const u16* A; const u16* B; u16* C; int N, nb;
  if (bx < nbx0) { A = A0; B = B0; C = C0; N = N0; nb = bx; }
  else           { A = A1; B = B1; C = C1; N = N1; nb = bx - nbx0; }
  const int mbase = by * 128, nbase = nb * 128;
  f32x4 acc[4][4] = {};
  for (int kb = 0; kb < 1024; kb += 32) {
    __syncthreads();
#pragma unroll
    for (int r = 0; r < 2; ++r) {
      int c = tid + 256 * r;
      int row = c >> 2, ch = c & 3;
      gld16(&A[(size_t)(mbase + row) * 1024 + kb + ch * 8], &Ab[c * 8]);
      gld16(&B[(size_t)(nbase + row) * 1024 + kb + ch * 8], &Bb[c * 8]);
    }
    __syncthreads();
    b16x8 af[4], bf[4];
#pragma unroll
    for (int mi = 0; mi < 4; ++mi)
      af[mi] = *(const b16x8*)&Ab[(wr * 64 + mi * 16 + q) * 32 + hi * 8];
#pragma unroll
    for (int ni = 0; ni < 4; ++ni)
      bf[ni] = *(const b16x8*)&Bb[(wc * 64 + ni * 16 + q) * 32 + hi * 8];
#pragma unroll
    for (int mi = 0; mi < 4; ++mi)
#pragma unroll
      for (int ni = 0; ni < 4; ++ni)
        acc[mi][ni] = mfma16(bf[ni], af[mi], acc[mi][ni]);  // D: rows=N, cols=M
  }
  // lane (q,hi) reg i holds C[mbase+wr*64+mi*16+q][nbase+wc*64+ni*16+hi*4+i]
#pragma unroll
  for (int mi = 0; mi < 4; ++mi) {
    const int m = mbase + wr * 64 + mi * 16 + q;
#pragma unroll
    for (int ni = 0; ni < 4; ++ni) {
      const int nc = nbase + wc * 64 + ni * 16 + hi * 4;
      uint2 o;
      o.x = cvtpk(acc[mi][ni][0], acc[mi][ni][1]);
      o.y = cvtpk(acc[mi][ni][2], acc[mi][ni][3]);
      *(uint2*)&C[(size_t)m * N + nc] = o;
    }
  }
}

// ---------------- V transpose: in[b*1024+k][coff+h*64+d] -> out[bh][d][k] ----
__global__ __launch_bounds__(256) void k_vt(const u16* __restrict__ in, int sIn,
                                            int coff, u16* __restrict__ out) {
  __shared__ u16 T[64 * 72];
  const int tid = threadIdx.x;
  const int bh = blockIdx.y, kb = blockIdx.x * 64;
  const int b = bh >> 4, h = bh & 15;
  const int kvp = tid >> 3, ch = tid & 7;
  const u16* p = in + (size_t)(b * 1024 + kb + 2 * kvp) * sIn + coff + h * 64 + ch * 8;
  b16x8 r0 = *(const b16x8*)p;
  b16x8 r1 = *(const b16x8*)(p + sIn);
#pragma unroll
  for (int j = 0; j < 8; ++j) {
    int i = (j + ch) & 7;
    uint32_t pk = (uint32_t)(u16)r0[i] | ((uint32_t)(u16)r1[i] << 16);
    *(uint32_t*)&T[(ch * 8 + i) * 72 + 2 * kvp] = pk;
  }
  __syncthreads();
  const int d = tid >> 2, seg = tid & 3;
  b16x8 v0 = *(const b16x8*)&T[d * 72 + seg * 16];
  b16x8 v1 = *(const b16x8*)&T[d * 72 + seg * 16 + 8];
  u16* o = out + (size_t)(bh * 64 + d) * 1024 + kb + seg * 16;
  *(b16x8*)o = v0;
  *(b16x8*)(o + 8) = v1;
}

// ---------------- flash attention, 4-wave LDS-staged (R5-verified) --------
template <int CAUSAL, typename OT>
__global__ __launch_bounds__(256, 3) void attn4(
    const u16* __restrict__ Qp, int sQ,
    const u16* __restrict__ Kp, int sK, int koff,
    const u16* __restrict__ Vt,  // [bh][64 d][1024 kv]
    OT* __restrict__ Op, int sO) {
  __shared__ u16 Ksh[2][64 * 64];
  __shared__ u16 Vsh[2][64 * 64];
  __shared__ u16 Plds[4][32 * 72];
  const int tid = threadIdx.x;
  const int lane = tid & 63, w = tid >> 6;
  const int lq = lane & 15, hi = lane >> 4;

  const int id = blockIdx.y * gridDim.x + blockIdx.x;  // grid (8, 64)
  const int xcd = id & 7, l = id >> 3;
  const int bh = xcd * 8 + (l >> 3);
  const int qb = (l < 32) ? (l & 7) : 7 - (l & 7);

  const size_t rowb = (size_t)(bh >> 4) * 1024;
  const int h = bh & 15;
  const int qw0 = qb * 128 + w * 32;
  const int nt = CAUSAL ? 2 * qb + 2 : 16;

  const u16* Kbase = Kp + rowb * (size_t)sK + koff + h * 64;
  const u16* Vbase = Vt + (size_t)bh * 65536;
  const u16* Qb = Qp + (rowb + qw0 + lq) * (size_t)sQ + h * 64 + hi * 8;
  u16* Pw = &Plds[w][0];

  b16x8 qf[2][2];
  qf[0][0] = *(const b16x8*)Qb;
  qf[0][1] = *(const b16x8*)(Qb + 32);
  qf[1][0] = *(const b16x8*)(Qb + (size_t)16 * sQ);
  qf[1][1] = *(const b16x8*)(Qb + (size_t)16 * sQ + 32);

  b16x8 ones;
#pragma unroll
  for (int i = 0; i < 8; ++i) ones[i] = (short)0x3F80;

  const int key = lq & 7;

  f32x4 acc[2][4] = {};
  f32x4 accl[2] = {};
  float m0 = -1e30f, m1 = -1e30f;

  auto stage = [&](int bf, int kt2) {
    const int kb2 = kt2 * 64;
#pragma unroll
    for (int r = 0; r < 2; ++r) {
      int c = tid + 256 * r;
      int row = c >> 3, ch = c & 7;
      int sw = row & 7;
      gld16(&Kbase[(size_t)(kb2 + row) * sK + ((ch ^ sw) << 3)],
            &Ksh[bf][c * 8]);
      gld16(&Vbase[(size_t)row * 1024 + kb2 + ((ch ^ sw) << 3)],
            &Vsh[bf][c * 8]);
    }
  };

  stage(0, 0);
  for (int kt = 0; kt < nt; ++kt) {
    __syncthreads();
    if (kt + 1 < nt) stage((kt + 1) & 1, kt + 1);
    const int kb = kt * 64;
    if (CAUSAL && kb > qw0 + 31) continue;
    const u16* Kl = Ksh[kt & 1];
    const u16* Vl = Vsh[kt & 1];

    f32x4 st[2][4];
#pragma unroll
    for (int t = 0; t < 4; ++t) {
      const int row = 16 * t + lq;
      b16x8 k0 = *(const b16x8*)&Kl[row * 64 + ((hi ^ key) << 3)];
      b16x8 k1 = *(const b16x8*)&Kl[row * 64 + (((4 + hi) ^ key) << 3)];
      f32x4 z0 = {}, z1 = {};
      z0 = mfma16(k0, qf[0][0], z0);
      st[0][t] = mfma16(k1, qf[0][1], z0);
      z1 = mfma16(k0, qf[1][0], z1);
      st[1][t] = mfma16(k1, qf[1][1], z1);
    }

    const bool dm = CAUSAL && (kb + 63 > qw0);
    float pm[2];
#pragma unroll
    for (int g = 0; g < 2; ++g) {
      if (dm) {
        const int qg = qw0 + g * 16 + lq;
#pragma unroll
        for (int t = 0; t < 4; ++t)
#pragma unroll
          for (int i = 0; i < 4; ++i)
            if (kb + 16 * t + 4 * hi + i > qg) st[g][t][i] = -INFINITY;
      }
      float m = -INFINITY;
#pragma unroll
      for (int t = 0; t < 4; ++t)
#pragma unroll
        for (int i = 0; i < 4; ++i) m = fmaxf(m, st[g][t][i]);
      m = fmaxf(m, __shfl_xor(m, 16));
      m = fmaxf(m, __shfl_xor(m, 32));
      pm[g] = m;
    }

    if (!__all((pm[0] <= m0 + 10.f) && (pm[1] <= m1 + 10.f))) {
      float n0 = fmaxf(m0, pm[0]), n1 = fmaxf(m1, pm[1]);
      float f0 = ex2(m0 - n0), f1 = ex2(m1 - n1);
#pragma unroll
      for (int t = 0; t < 4; ++t)
#pragma unroll
        for (int i = 0; i < 4; ++i) {
          acc[0][t][i] *= f0;
          acc[1][t][i] *= f1;
        }
#pragma unroll
      for (int i = 0; i < 4; ++i) { accl[0][i] *= f0; accl[1][i] *= f1; }
      m0 = n0; m1 = n1;
    }

#pragma unroll
    for (int g = 0; g < 2; ++g) {
      const float mm = g ? m1 : m0;
#pragma unroll
      for (int t = 0; t < 4; ++t) {
        uint2 pw;
        pw.x = cvtpk(ex2(st[g][t][0] - mm), ex2(st[g][t][1] - mm));
        pw.y = cvtpk(ex2(st[g][t][2] - mm), ex2(st[g][t][3] - mm));
        *(uint2*)&Pw[(g * 16 + lq) * 72 + 16 * t + 4 * hi] = pw;
      }
    }

    b16x8 av0[4], av1[4];
#pragma unroll
    for (int t = 0; t < 4; ++t) {
      const int rv = 16 * t + lq;
      av0[t] = *(const b16x8*)&Vl[rv * 64 + ((hi ^ key) << 3)];
      av1[t] = *(const b16x8*)&Vl[rv * 64 + (((4 + hi) ^ key) << 3)];
    }

#pragma unroll
    for (int g = 0; g < 2; ++g) {
      b16x8 bp0 = *(const b16x8*)&Pw[(g * 16 + lq) * 72 + hi * 8];
      b16x8 bp1 = *(const b16x8*)&Pw[(g * 16 + lq) * 72 + 32 + hi * 8];
      accl[g] = mfma16(ones, bp0, accl[g]);
      accl[g] = mfma16(ones, bp1, accl[g]);
#pragma unroll
      for (int t = 0; t < 4; ++t) {
        acc[g][t] = mfma16(av0[t], bp0, acc[g][t]);
        acc[g][t] = mfma16(av1[t], bp1, acc[g][t]);
      }
    }
  }

#pragma unroll
  for (int g = 0; g < 2; ++g) {
    const float inv = 1.0f / accl[g][0];
    const size_t ob = (rowb + qw0 + g * 16 + lq) * (size_t)sO + h * 64;
#pragma unroll
    for (int t = 0; t < 4; ++t) {
      const int d = 16 * t + 4 * hi;
      if constexpr (sizeof(OT) == 2) {
        b16x4 o;
        o[0] = (short)f2bf(acc[g][t][0] * inv);
        o[1] = (short)f2bf(acc[g][t][1] * inv);
        o[2] = (short)f2bf(acc[g][t][2] * inv);
        o[3] = (short)f2bf(acc[g][t][3] * inv);
        *(b16x4*)&((u16*)Op)[ob + d] = o;
      } else {
        float4 o = make_float4(acc[g][t][0] * inv, acc[g][t][1] * inv,
                               acc[g][t][2] * inv, acc[g][t][3] * inv);
        *(float4*)&((float*)Op)[ob + d] = o;
      }
    }
  }
}

extern "C" void kernel_launch(void* const* d_in, const int* in_sizes, int n_in,
                              void* d_out, int out_size, void* d_ws, size_t ws_size,
                              hipStream_t stream) {
  (void)in_sizes; (void)n_in; (void)out_size; (void)ws_size;
  const float* x   = (const float*)d_in[0];
  const float* enc = (const float*)d_in[1];
  const float* wqs = (const float*)d_in[4];
  const float* wks = (const float*)d_in[5];
  const float* wvs = (const float*)d_in[6];
  const float* wqc = (const float*)d_in[7];
  const float* wkc = (const float*)d_in[8];
  const float* wvc = (const float*)d_in[9];

  u16* ws   = (u16*)d_ws;
  u16* xb   = ws;                  // 4096x1024 ; reused as V1^T after QKV1
  u16* encb = ws + 4194304;        // 4096x1024 ; reused as V2^T after KV2
  u16* wsc  = ws + 8388608;        // 3x 1024x1024
  u16* wcc  = ws + 11534336;       // 3x 1024x1024
  u16* qkv1 = ws + 14680064;       // 4096x3072
  u16* x1b  = ws + 27262976;       // 4096x1024
  u16* q2   = ws + 31457280;       // 4096x1024
  u16* kv2  = ws + 35651584;       // 4096x2048

  k_cvt_all<<<7168, 256, 0, stream>>>(x, enc, wqs, wks, wvs, wqc, wkc, wvc,
                                      xb, encb, wsc, wcc);

  // layer 1: QKV projection (single problem -> both sets identical)
  k_gemm_bt<<<dim3(24, 32), 256, 0, stream>>>(xb, wsc, qkv1, 3072, 24,
                                              xb, wsc, qkv1, 3072);
  k_vt<<<dim3(16, 64), 256, 0, stream>>>(qkv1, 3072, 2048, xb);  // V1^T
  attn4<1, u16><<<dim3(8, 64), 256, 0, stream>>>(
      qkv1, 3072, qkv1, 3072, 1024, xb, x1b, 1024);

  // layer 2: Q2 (bx<8) + KV2 (bx>=8) fused in one dispatch
  k_gemm_bt<<<dim3(24, 32), 256, 0, stream>>>(x1b, wcc, q2, 1024, 8,
                                              encb, wcc + 1048576, kv2, 2048);
  k_vt<<<dim3(16, 64), 256, 0, stream>>>(kv2, 2048, 1024, encb);  // V2^T
  attn4<0, float><<<dim3(8, 64), 256, 0, stream>>>(
      q2, 1024, kv2, 2048, 0, encb, (float*)d_out, 1024);
}

// Round 7
// 273.305 us; speedup vs baseline: 1.0251x; 1.0251x over previous
//
#include <hip/hip_runtime.h>
#include <stdint.h>

// R7: revert GEMM to R5-pinned body (R6's swapped epilogue + mux regressed:
// VGPR 68->92, FETCH 2x). New: V-projection tiles write V^T directly from the
// GEMM epilogue (lane's 4 regs = 4 consecutive kv at fixed d -> one uint2
// store), removing both k_vt dispatches. attn4 byte-identical to R5.
// B=4 S=1024 D=1024 H=16 DK=64.

typedef unsigned short u16;
typedef short b16x8 __attribute__((ext_vector_type(8)));
typedef short b16x4 __attribute__((ext_vector_type(4)));
typedef float f32x4 __attribute__((ext_vector_type(4)));

__device__ __forceinline__ u16 f2bf(float f) {
  union { float f; uint32_t u; } v; v.f = f;
  uint32_t r = v.u + 0x7fffu + ((v.u >> 16) & 1u);
  return (u16)(r >> 16);
}

__device__ __forceinline__ f32x4 mfma16(b16x8 a, b16x8 b, f32x4 c) {
  return __builtin_amdgcn_mfma_f32_16x16x32_bf16(a, b, c, 0, 0, 0);
}

__device__ __forceinline__ void gld16(const void* g, void* l) {
  __builtin_amdgcn_global_load_lds(
      (const __attribute__((address_space(1))) void*)g,
      (__attribute__((address_space(3))) void*)l, 16, 0, 0);
}

__device__ __forceinline__ float ex2(float x) {
  float r; asm("v_exp_f32 %0, %1" : "=v"(r) : "v"(x)); return r;
}

__device__ __forceinline__ uint32_t cvtpk(float a, float b) {
  uint32_t r;
  asm("v_cvt_pk_bf16_f32 %0, %1, %2" : "=v"(r) : "v"(a), "v"(b));
  return r;
}

// ---------------- fused f32 -> bf16 convert (x, enc, 6 weights) ----------
// blocks: [0,2048) x ; [2048,4096) enc ; [4096,7168) weights (512 each).
__global__ __launch_bounds__(256) void k_cvt_all(
    const float* __restrict__ x, const float* __restrict__ enc,
    const float* __restrict__ w0, const float* __restrict__ w1,
    const float* __restrict__ w2, const float* __restrict__ w3,
    const float* __restrict__ w4, const float* __restrict__ w5,
    u16* __restrict__ xb, u16* __restrict__ encb,
    u16* __restrict__ wsc, u16* __restrict__ wcc) {
  const int id = blockIdx.x;
  const float* in;
  u16* out;
  float sc = 1.0f;
  int off;
  if (id < 2048) {
    in = x; out = xb; off = id;
  } else if (id < 4096) {
    in = enc; out = encb; off = id - 2048;
  } else {
    const int wi = (id - 4096) >> 9;
    off = (id - 4096) & 511;
    switch (wi) {
      case 0: in = w0; break; case 1: in = w1; break; case 2: in = w2; break;
      case 3: in = w3; break; case 4: in = w4; break; default: in = w5; break;
    }
    out = (wi < 3 ? wsc : wcc) + (wi % 3) * 1048576;
    if (wi % 3 == 0) sc = 0.18033688f;  // 0.125 * log2(e) folded into wq
  }
  const int i = (off * 256 + threadIdx.x) * 8;
  float4 a = *(const float4*)(in + i);
  float4 b = *(const float4*)(in + i + 4);
  b16x8 v;
  v[0] = (short)f2bf(a.x * sc); v[1] = (short)f2bf(a.y * sc);
  v[2] = (short)f2bf(a.z * sc); v[3] = (short)f2bf(a.w * sc);
  v[4] = (short)f2bf(b.x * sc); v[5] = (short)f2bf(b.y * sc);
  v[6] = (short)f2bf(b.z * sc); v[7] = (short)f2bf(b.w * sc);
  *(b16x8*)(out + i) = v;
}

// ---------------- bf16 GEMM: C[M,N] = A[M,K].B[N,K]^T (R5-pinned body) ----
// M=4096, K=1024 fixed; 128x128 tile, BK=32. N-tiles with nbase >= vcol0 are
// V-projection tiles: written ONLY as V^T[bh][d][kv] (uint2, 4 kv per lane).
__global__ __launch_bounds__(256) void k_gemm_bt(
    const u16* __restrict__ A, const u16* __restrict__ B,
    u16* __restrict__ C, int N, u16* __restrict__ vt, int vcol0) {
  __shared__ u16 Ab[128 * 32];
  __shared__ u16 Bb[128 * 32];
  const int tid = threadIdx.x;
  const int lane = tid & 63, w = tid >> 6;
  const int wr = w >> 1, wc = w & 1;
  const int q = lane & 15, hi = lane >> 4;
  const int nwg = gridDim.x * gridDim.y;
  const int id = blockIdx.y * gridDim.x + blockIdx.x;
  const int swz = (id & 7) * (nwg >> 3) + (id >> 3);  // bijective (nwg%8==0)
  const int bx = swz % gridDim.x, by = swz / gridDim.x;
  const int mbase = by * 128, nbase = bx * 128;
  f32x4 acc[4][4] = {};
  for (int kb = 0; kb < 1024; kb += 32) {
    __syncthreads();
#pragma unroll
    for (int r = 0; r < 2; ++r) {
      int c = tid + 256 * r;
      int row = c >> 2, ch = c & 3;
      gld16(&A[(size_t)(mbase + row) * 1024 + kb + ch * 8], &Ab[c * 8]);
      gld16(&B[(size_t)(nbase + row) * 1024 + kb + ch * 8], &Bb[c * 8]);
    }
    __syncthreads();
    b16x8 af[4], bf[4];
#pragma unroll
    for (int mi = 0; mi < 4; ++mi)
      af[mi] = *(const b16x8*)&Ab[(wr * 64 + mi * 16 + q) * 32 + hi * 8];
#pragma unroll
    for (int ni = 0; ni < 4; ++ni)
      bf[ni] = *(const b16x8*)&Bb[(wc * 64 + ni * 16 + q) * 32 + hi * 8];
#pragma unroll
    for (int mi = 0; mi < 4; ++mi)
#pragma unroll
      for (int ni = 0; ni < 4; ++ni)
        acc[mi][ni] = mfma16(af[mi], bf[ni], acc[mi][ni]);
  }
  if (nbase >= vcol0) {
    // V^T direct write: reg i of (mi,ni) = C[m0+i][n0] = V[kv0+i][d]
    const int hc = nbase - vcol0;
#pragma unroll
    for (int mi = 0; mi < 4; ++mi) {
      const int m0 = mbase + wr * 64 + mi * 16 + hi * 4;
      const int bh16 = (m0 >> 10) * 16;
      const int kv = m0 & 1023;
#pragma unroll
      for (int ni = 0; ni < 4; ++ni) {
        const int n0 = hc + wc * 64 + ni * 16 + q;
        const int bh = bh16 + (n0 >> 6), d = n0 & 63;
        uint2 o;
        o.x = cvtpk(acc[mi][ni][0], acc[mi][ni][1]);
        o.y = cvtpk(acc[mi][ni][2], acc[mi][ni][3]);
        *(uint2*)&vt[(size_t)bh * 65536 + d * 1024 + kv] = o;
      }
    }
  } else {
#pragma unroll
    for (int mi = 0; mi < 4; ++mi)
#pragma unroll
      for (int ni = 0; ni < 4; ++ni) {
        int m0 = mbase + wr * 64 + mi * 16 + hi * 4;
        int n0 = nbase + wc * 64 + ni * 16 + q;
#pragma unroll
        for (int i = 0; i < 4; ++i)
          C[(size_t)(m0 + i) * N + n0] = f2bf(acc[mi][ni][i]);
      }
  }
}

// ---------------- flash attention, 4-wave LDS-staged (R5-verified) --------
template <int CAUSAL, typename OT>
__global__ __launch_bounds__(256, 3) void attn4(
    const u16* __restrict__ Qp, int sQ,
    const u16* __restrict__ Kp, int sK, int koff,
    const u16* __restrict__ Vt,  // [bh][64 d][1024 kv]
    OT* __restrict__ Op, int sO) {
  __shared__ u16 Ksh[2][64 * 64];
  __shared__ u16 Vsh[2][64 * 64];
  __shared__ u16 Plds[4][32 * 72];
  const int tid = threadIdx.x;
  const int lane = tid & 63, w = tid >> 6;
  const int lq = lane & 15, hi = lane >> 4;

  const int id = blockIdx.y * gridDim.x + blockIdx.x;  // grid (8, 64)
  const int xcd = id & 7, l = id >> 3;
  const int bh = xcd * 8 + (l >> 3);
  const int qb = (l < 32) ? (l & 7) : 7 - (l & 7);

  const size_t rowb = (size_t)(bh >> 4) * 1024;
  const int h = bh & 15;
  const int qw0 = qb * 128 + w * 32;
  const int nt = CAUSAL ? 2 * qb + 2 : 16;

  const u16* Kbase = Kp + rowb * (size_t)sK + koff + h * 64;
  const u16* Vbase = Vt + (size_t)bh * 65536;
  const u16* Qb = Qp + (rowb + qw0 + lq) * (size_t)sQ + h * 64 + hi * 8;
  u16* Pw = &Plds[w][0];

  b16x8 qf[2][2];
  qf[0][0] = *(const b16x8*)Qb;
  qf[0][1] = *(const b16x8*)(Qb + 32);
  qf[1][0] = *(const b16x8*)(Qb + (size_t)16 * sQ);
  qf[1][1] = *(const b16x8*)(Qb + (size_t)16 * sQ + 32);

  b16x8 ones;
#pragma unroll
  for (int i = 0; i < 8; ++i) ones[i] = (short)0x3F80;

  const int key = lq & 7;

  f32x4 acc[2][4] = {};
  f32x4 accl[2] = {};
  float m0 = -1e30f, m1 = -1e30f;

  auto stage = [&](int bf, int kt2) {
    const int kb2 = kt2 * 64;
#pragma unroll
    for (int r = 0; r < 2; ++r) {
      int c = tid + 256 * r;
      int row = c >> 3, ch = c & 7;
      int sw = row & 7;
      gld16(&Kbase[(size_t)(kb2 + row) * sK + ((ch ^ sw) << 3)],
            &Ksh[bf][c * 8]);
      gld16(&Vbase[(size_t)row * 1024 + kb2 + ((ch ^ sw) << 3)],
            &Vsh[bf][c * 8]);
    }
  };

  stage(0, 0);
  for (int kt = 0; kt < nt; ++kt) {
    __syncthreads();
    if (kt + 1 < nt) stage((kt + 1) & 1, kt + 1);
    const int kb = kt * 64;
    if (CAUSAL && kb > qw0 + 31) continue;
    const u16* Kl = Ksh[kt & 1];
    const u16* Vl = Vsh[kt & 1];

    f32x4 st[2][4];
#pragma unroll
    for (int t = 0; t < 4; ++t) {
      const int row = 16 * t + lq;
      b16x8 k0 = *(const b16x8*)&Kl[row * 64 + ((hi ^ key) << 3)];
      b16x8 k1 = *(const b16x8*)&Kl[row * 64 + (((4 + hi) ^ key) << 3)];
      f32x4 z0 = {}, z1 = {};
      z0 = mfma16(k0, qf[0][0], z0);
      st[0][t] = mfma16(k1, qf[0][1], z0);
      z1 = mfma16(k0, qf[1][0], z1);
      st[1][t] = mfma16(k1, qf[1][1], z1);
    }

    const bool dm = CAUSAL && (kb + 63 > qw0);
    float pm[2];
#pragma unroll
    for (int g = 0; g < 2; ++g) {
      if (dm) {
        const int qg = qw0 + g * 16 + lq;
#pragma unroll
        for (int t = 0; t < 4; ++t)
#pragma unroll
          for (int i = 0; i < 4; ++i)
            if (kb + 16 * t + 4 * hi + i > qg) st[g][t][i] = -INFINITY;
      }
      float m = -INFINITY;
#pragma unroll
      for (int t = 0; t < 4; ++t)
#pragma unroll
        for (int i = 0; i < 4; ++i) m = fmaxf(m, st[g][t][i]);
      m = fmaxf(m, __shfl_xor(m, 16));
      m = fmaxf(m, __shfl_xor(m, 32));
      pm[g] = m;
    }

    if (!__all((pm[0] <= m0 + 10.f) && (pm[1] <= m1 + 10.f))) {
      float n0 = fmaxf(m0, pm[0]), n1 = fmaxf(m1, pm[1]);
      float f0 = ex2(m0 - n0), f1 = ex2(m1 - n1);
#pragma unroll
      for (int t = 0; t < 4; ++t)
#pragma unroll
        for (int i = 0; i < 4; ++i) {
          acc[0][t][i] *= f0;
          acc[1][t][i] *= f1;
        }
#pragma unroll
      for (int i = 0; i < 4; ++i) { accl[0][i] *= f0; accl[1][i] *= f1; }
      m0 = n0; m1 = n1;
    }

#pragma unroll
    for (int g = 0; g < 2; ++g) {
      const float mm = g ? m1 : m0;
#pragma unroll
      for (int t = 0; t < 4; ++t) {
        uint2 pw;
        pw.x = cvtpk(ex2(st[g][t][0] - mm), ex2(st[g][t][1] - mm));
        pw.y = cvtpk(ex2(st[g][t][2] - mm), ex2(st[g][t][3] - mm));
        *(uint2*)&Pw[(g * 16 + lq) * 72 + 16 * t + 4 * hi] = pw;
      }
    }

    b16x8 av0[4], av1[4];
#pragma unroll
    for (int t = 0; t < 4; ++t) {
      const int rv = 16 * t + lq;
      av0[t] = *(const b16x8*)&Vl[rv * 64 + ((hi ^ key) << 3)];
      av1[t] = *(const b16x8*)&Vl[rv * 64 + (((4 + hi) ^ key) << 3)];
    }

#pragma unroll
    for (int g = 0; g < 2; ++g) {
      b16x8 bp0 = *(const b16x8*)&Pw[(g * 16 + lq) * 72 + hi * 8];
      b16x8 bp1 = *(const b16x8*)&Pw[(g * 16 + lq) * 72 + 32 + hi * 8];
      accl[g] = mfma16(ones, bp0, accl[g]);
      accl[g] = mfma16(ones, bp1, accl[g]);
#pragma unroll
      for (int t = 0; t < 4; ++t) {
        acc[g][t] = mfma16(av0[t], bp0, acc[g][t]);
        acc[g][t] = mfma16(av1[t], bp1, acc[g][t]);
      }
    }
  }

#pragma unroll
  for (int g = 0; g < 2; ++g) {
    const float inv = 1.0f / accl[g][0];
    const size_t ob = (rowb + qw0 + g * 16 + lq) * (size_t)sO + h * 64;
#pragma unroll
    for (int t = 0; t < 4; ++t) {
      const int d = 16 * t + 4 * hi;
      if constexpr (sizeof(OT) == 2) {
        b16x4 o;
        o[0] = (short)f2bf(acc[g][t][0] * inv);
        o[1] = (short)f2bf(acc[g][t][1] * inv);
        o[2] = (short)f2bf(acc[g][t][2] * inv);
        o[3] = (short)f2bf(acc[g][t][3] * inv);
        *(b16x4*)&((u16*)Op)[ob + d] = o;
      } else {
        float4 o = make_float4(acc[g][t][0] * inv, acc[g][t][1] * inv,
                               acc[g][t][2] * inv, acc[g][t][3] * inv);
        *(float4*)&((float*)Op)[ob + d] = o;
      }
    }
  }
}

extern "C" void kernel_launch(void* const* d_in, const int* in_sizes, int n_in,
                              void* d_out, int out_size, void* d_ws, size_t ws_size,
                              hipStream_t stream) {
  (void)in_sizes; (void)n_in; (void)out_size; (void)ws_size;
  const float* x   = (const float*)d_in[0];
  const float* enc = (const float*)d_in[1];
  const float* wqs = (const float*)d_in[4];
  const float* wks = (const float*)d_in[5];
  const float* wvs = (const float*)d_in[6];
  const float* wqc = (const float*)d_in[7];
  const float* wkc = (const float*)d_in[8];
  const float* wvc = (const float*)d_in[9];

  u16* ws   = (u16*)d_ws;
  u16* xb   = ws;                  // 4096x1024 A of QKV1; reused as V2^T
  u16* encb = ws + 4194304;        // 4096x1024 A of KV2
  u16* wsc  = ws + 8388608;        // 3x 1024x1024
  u16* wcc  = ws + 11534336;       // 3x 1024x1024
  u16* qkv1 = ws + 14680064;       // 4096x3072 (V third left unwritten)
  u16* x1b  = ws + 27262976;       // 4096x1024 attn1 out
  u16* q2   = ws + 31457280;       // 4096x1024 ; V1^T first, then Q2 out
  u16* kv2  = ws + 35651584;       // 4096x2048 (V half left unwritten)

  k_cvt_all<<<7168, 256, 0, stream>>>(x, enc, wqs, wks, wvs, wqc, wkc, wvc,
                                      xb, encb, wsc, wcc);

  // layer 1: QKV projection; V third written directly as V1^T into q2 region
  k_gemm_bt<<<dim3(24, 32), 256, 0, stream>>>(xb, wsc, qkv1, 3072, q2, 2048);
  attn4<1, u16><<<dim3(8, 64), 256, 0, stream>>>(
      qkv1, 3072, qkv1, 3072, 1024, q2, x1b, 1024);

  // layer 2: Q2 plain; KV2 writes K half + V2^T (into xb, dead after QKV1)
  k_gemm_bt<<<dim3(8, 32), 256, 0, stream>>>(x1b, wcc, q2, 1024, q2, 1 << 28);
  k_gemm_bt<<<dim3(16, 32), 256, 0, stream>>>(encb, wcc + 1048576, kv2, 2048,
                                              xb, 1024);
  attn4<0, float><<<dim3(8, 64), 256, 0, stream>>>(
      q2, 1024, kv2, 2048, 0, xb, (float*)d_out, 1024);
}

// Round 8
// 258.345 us; speedup vs baseline: 1.0845x; 1.0579x over previous
//
#include <hip/hip_runtime.h>
#include <stdint.h>

// R8: GEMM reverted to exact R5 body+epilogue (R6/R7 post-mortem: V^T-direct
// epilogue caused VGPR 68->92 + RFO FETCH 2x; mux was innocent). New layout:
// KV2 fused into QKV1 dispatch (independent of attn1) -> 5 blocks/CU; both
// V-transposes fused into one dispatch. attn4 byte-identical to R5.
// B=4 S=1024 D=1024 H=16 DK=64.

typedef unsigned short u16;
typedef short b16x8 __attribute__((ext_vector_type(8)));
typedef short b16x4 __attribute__((ext_vector_type(4)));
typedef float f32x4 __attribute__((ext_vector_type(4)));

__device__ __forceinline__ u16 f2bf(float f) {
  union { float f; uint32_t u; } v; v.f = f;
  uint32_t r = v.u + 0x7fffu + ((v.u >> 16) & 1u);
  return (u16)(r >> 16);
}

__device__ __forceinline__ f32x4 mfma16(b16x8 a, b16x8 b, f32x4 c) {
  return __builtin_amdgcn_mfma_f32_16x16x32_bf16(a, b, c, 0, 0, 0);
}

__device__ __forceinline__ void gld16(const void* g, void* l) {
  __builtin_amdgcn_global_load_lds(
      (const __attribute__((address_space(1))) void*)g,
      (__attribute__((address_space(3))) void*)l, 16, 0, 0);
}

__device__ __forceinline__ float ex2(float x) {
  float r; asm("v_exp_f32 %0, %1" : "=v"(r) : "v"(x)); return r;
}

__device__ __forceinline__ uint32_t cvtpk(float a, float b) {
  uint32_t r;
  asm("v_cvt_pk_bf16_f32 %0, %1, %2" : "=v"(r) : "v"(a), "v"(b));
  return r;
}

// ---------------- fused f32 -> bf16 convert (x, enc, 6 weights) ----------
__global__ __launch_bounds__(256) void k_cvt_all(
    const float* __restrict__ x, const float* __restrict__ enc,
    const float* __restrict__ w0, const float* __restrict__ w1,
    const float* __restrict__ w2, const float* __restrict__ w3,
    const float* __restrict__ w4, const float* __restrict__ w5,
    u16* __restrict__ xb, u16* __restrict__ encb,
    u16* __restrict__ wsc, u16* __restrict__ wcc) {
  const int id = blockIdx.x;
  const float* in;
  u16* out;
  float sc = 1.0f;
  int off;
  if (id < 2048) {
    in = x; out = xb; off = id;
  } else if (id < 4096) {
    in = enc; out = encb; off = id - 2048;
  } else {
    const int wi = (id - 4096) >> 9;
    off = (id - 4096) & 511;
    switch (wi) {
      case 0: in = w0; break; case 1: in = w1; break; case 2: in = w2; break;
      case 3: in = w3; break; case 4: in = w4; break; default: in = w5; break;
    }
    out = (wi < 3 ? wsc : wcc) + (wi % 3) * 1048576;
    if (wi % 3 == 0) sc = 0.18033688f;  // 0.125 * log2(e) folded into wq
  }
  const int i = (off * 256 + threadIdx.x) * 8;
  float4 a = *(const float4*)(in + i);
  float4 b = *(const float4*)(in + i + 4);
  b16x8 v;
  v[0] = (short)f2bf(a.x * sc); v[1] = (short)f2bf(a.y * sc);
  v[2] = (short)f2bf(a.z * sc); v[3] = (short)f2bf(a.w * sc);
  v[4] = (short)f2bf(b.x * sc); v[5] = (short)f2bf(b.y * sc);
  v[6] = (short)f2bf(b.z * sc); v[7] = (short)f2bf(b.w * sc);
  *(b16x8*)(out + i) = v;
}

// -------- bf16 GEMM: C[M,N] = A[M,K].B[N,K]^T  (R5-pinned body+epilogue) --
// M=4096, K=1024 fixed; 128x128 tile, BK=32. Dual-problem mux: bx < nbx0 ->
// set0, else set1 (mux is SGPR-only; epilogue/write pattern untouched).
__global__ __launch_bounds__(256) void k_gemm_bt(
    const u16* __restrict__ A0, const u16* __restrict__ B0,
    u16* __restrict__ C0, int N0, int nbx0,
    const u16* __restrict__ A1, const u16* __restrict__ B1,
    u16* __restrict__ C1, int N1) {
  __shared__ u16 Ab[128 * 32];
  __shared__ u16 Bb[128 * 32];
  const int tid = threadIdx.x;
  const int lane = tid & 63, w = tid >> 6;
  const int wr = w >> 1, wc = w & 1;
  const int q = lane & 15, hi = lane >> 4;
  const int nwg = gridDim.x * gridDim.y;
  const int id = blockIdx.y * gridDim.x + blockIdx.x;
  const int swz = (id & 7) * (nwg >> 3) + (id >> 3);  // bijective (nwg%8==0)
  const int bx = swz % gridDim.x, by = swz / gridDim.x;
  const u16* A; const u16* B; u16* C; int N, nb;
  if (bx < nbx0) { A = A0; B = B0; C = C0; N = N0; nb = bx; }
  else           { A = A1; B = B1; C = C1; N = N1; nb = bx - nbx0; }
  const int mbase = by * 128, nbase = nb * 128;
  f32x4 acc[4][4] = {};
  for (int kb = 0; kb < 1024; kb += 32) {
    __syncthreads();
#pragma unroll
    for (int r = 0; r < 2; ++r) {
      int c = tid + 256 * r;
      int row = c >> 2, ch = c & 3;
      gld16(&A[(size_t)(mbase + row) * 1024 + kb + ch * 8], &Ab[c * 8]);
      gld16(&B[(size_t)(nbase + row) * 1024 + kb + ch * 8], &Bb[c * 8]);
    }
    __syncthreads();
    b16x8 af[4], bf[4];
#pragma unroll
    for (int mi = 0; mi < 4; ++mi)
      af[mi] = *(const b16x8*)&Ab[(wr * 64 + mi * 16 + q) * 32 + hi * 8];
#pragma unroll
    for (int ni = 0; ni < 4; ++ni)
      bf[ni] = *(const b16x8*)&Bb[(wc * 64 + ni * 16 + q) * 32 + hi * 8];
#pragma unroll
    for (int mi = 0; mi < 4; ++mi)
#pragma unroll
      for (int ni = 0; ni < 4; ++ni)
        acc[mi][ni] = mfma16(af[mi], bf[ni], acc[mi][ni]);
  }
#pragma unroll
  for (int mi = 0; mi < 4; ++mi)
#pragma unroll
    for (int ni = 0; ni < 4; ++ni) {
      int m0 = mbase + wr * 64 + mi * 16 + hi * 4;
      int n0 = nbase + wc * 64 + ni * 16 + q;
#pragma unroll
      for (int i = 0; i < 4; ++i)
        C[(size_t)(m0 + i) * N + n0] = f2bf(acc[mi][ni][i]);
    }
}

// ---- fused V transposes: sel=blockIdx.y>>6 picks (in,stride,coff,out) ----
// in[b*1024+k][coff+h*64+d] -> out[bh][d][k]
__global__ __launch_bounds__(256) void k_vt2x(
    const u16* __restrict__ in0, int s0, int c0, u16* __restrict__ out0,
    const u16* __restrict__ in1, int s1, int c1, u16* __restrict__ out1) {
  __shared__ u16 T[64 * 72];
  const int tid = threadIdx.x;
  const int sel = blockIdx.y >> 6;
  const u16* in = sel ? in1 : in0;
  u16* out = sel ? out1 : out0;
  const int sIn = sel ? s1 : s0, coff = sel ? c1 : c0;
  const int bh = blockIdx.y & 63, kb = blockIdx.x * 64;
  const int b = bh >> 4, h = bh & 15;
  const int kvp = tid >> 3, ch = tid & 7;
  const u16* p = in + (size_t)(b * 1024 + kb + 2 * kvp) * sIn + coff + h * 64 + ch * 8;
  b16x8 r0 = *(const b16x8*)p;
  b16x8 r1 = *(const b16x8*)(p + sIn);
#pragma unroll
  for (int j = 0; j < 8; ++j) {
    int i = (j + ch) & 7;
    uint32_t pk = (uint32_t)(u16)r0[i] | ((uint32_t)(u16)r1[i] << 16);
    *(uint32_t*)&T[(ch * 8 + i) * 72 + 2 * kvp] = pk;
  }
  __syncthreads();
  const int d = tid >> 2, seg = tid & 3;
  b16x8 v0 = *(const b16x8*)&T[d * 72 + seg * 16];
  b16x8 v1 = *(const b16x8*)&T[d * 72 + seg * 16 + 8];
  u16* o = out + (size_t)(bh * 64 + d) * 1024 + kb + seg * 16;
  *(b16x8*)o = v0;
  *(b16x8*)(o + 8) = v1;
}

// ---------------- flash attention, 4-wave LDS-staged (R5-verified) --------
template <int CAUSAL, typename OT>
__global__ __launch_bounds__(256, 3) void attn4(
    const u16* __restrict__ Qp, int sQ,
    const u16* __restrict__ Kp, int sK, int koff,
    const u16* __restrict__ Vt,  // [bh][64 d][1024 kv]
    OT* __restrict__ Op, int sO) {
  __shared__ u16 Ksh[2][64 * 64];
  __shared__ u16 Vsh[2][64 * 64];
  __shared__ u16 Plds[4][32 * 72];
  const int tid = threadIdx.x;
  const int lane = tid & 63, w = tid >> 6;
  const int lq = lane & 15, hi = lane >> 4;

  const int id = blockIdx.y * gridDim.x + blockIdx.x;  // grid (8, 64)
  const int xcd = id & 7, l = id >> 3;
  const int bh = xcd * 8 + (l >> 3);
  const int qb = (l < 32) ? (l & 7) : 7 - (l & 7);

  const size_t rowb = (size_t)(bh >> 4) * 1024;
  const int h = bh & 15;
  const int qw0 = qb * 128 + w * 32;
  const int nt = CAUSAL ? 2 * qb + 2 : 16;

  const u16* Kbase = Kp + rowb * (size_t)sK + koff + h * 64;
  const u16* Vbase = Vt + (size_t)bh * 65536;
  const u16* Qb = Qp + (rowb + qw0 + lq) * (size_t)sQ + h * 64 + hi * 8;
  u16* Pw = &Plds[w][0];

  b16x8 qf[2][2];
  qf[0][0] = *(const b16x8*)Qb;
  qf[0][1] = *(const b16x8*)(Qb + 32);
  qf[1][0] = *(const b16x8*)(Qb + (size_t)16 * sQ);
  qf[1][1] = *(const b16x8*)(Qb + (size_t)16 * sQ + 32);

  b16x8 ones;
#pragma unroll
  for (int i = 0; i < 8; ++i) ones[i] = (short)0x3F80;

  const int key = lq & 7;

  f32x4 acc[2][4] = {};
  f32x4 accl[2] = {};
  float m0 = -1e30f, m1 = -1e30f;

  auto stage = [&](int bf, int kt2) {
    const int kb2 = kt2 * 64;
#pragma unroll
    for (int r = 0; r < 2; ++r) {
      int c = tid + 256 * r;
      int row = c >> 3, ch = c & 7;
      int sw = row & 7;
      gld16(&Kbase[(size_t)(kb2 + row) * sK + ((ch ^ sw) << 3)],
            &Ksh[bf][c * 8]);
      gld16(&Vbase[(size_t)row * 1024 + kb2 + ((ch ^ sw) << 3)],
            &Vsh[bf][c * 8]);
    }
  };

  stage(0, 0);
  for (int kt = 0; kt < nt; ++kt) {
    __syncthreads();
    if (kt + 1 < nt) stage((kt + 1) & 1, kt + 1);
    const int kb = kt * 64;
    if (CAUSAL && kb > qw0 + 31) continue;
    const u16* Kl = Ksh[kt & 1];
    const u16* Vl = Vsh[kt & 1];

    f32x4 st[2][4];
#pragma unroll
    for (int t = 0; t < 4; ++t) {
      const int row = 16 * t + lq;
      b16x8 k0 = *(const b16x8*)&Kl[row * 64 + ((hi ^ key) << 3)];
      b16x8 k1 = *(const b16x8*)&Kl[row * 64 + (((4 + hi) ^ key) << 3)];
      f32x4 z0 = {}, z1 = {};
      z0 = mfma16(k0, qf[0][0], z0);
      st[0][t] = mfma16(k1, qf[0][1], z0);
      z1 = mfma16(k0, qf[1][0], z1);
      st[1][t] = mfma16(k1, qf[1][1], z1);
    }

    const bool dm = CAUSAL && (kb + 63 > qw0);
    float pm[2];
#pragma unroll
    for (int g = 0; g < 2; ++g) {
      if (dm) {
        const int qg = qw0 + g * 16 + lq;
#pragma unroll
        for (int t = 0; t < 4; ++t)
#pragma unroll
          for (int i = 0; i < 4; ++i)
            if (kb + 16 * t + 4 * hi + i > qg) st[g][t][i] = -INFINITY;
      }
      float m = -INFINITY;
#pragma unroll
      for (int t = 0; t < 4; ++t)
#pragma unroll
        for (int i = 0; i < 4; ++i) m = fmaxf(m, st[g][t][i]);
      m = fmaxf(m, __shfl_xor(m, 16));
      m = fmaxf(m, __shfl_xor(m, 32));
      pm[g] = m;
    }

    if (!__all((pm[0] <= m0 + 10.f) && (pm[1] <= m1 + 10.f))) {
      float n0 = fmaxf(m0, pm[0]), n1 = fmaxf(m1, pm[1]);
      float f0 = ex2(m0 - n0), f1 = ex2(m1 - n1);
#pragma unroll
      for (int t = 0; t < 4; ++t)
#pragma unroll
        for (int i = 0; i < 4; ++i) {
          acc[0][t][i] *= f0;
          acc[1][t][i] *= f1;
        }
#pragma unroll
      for (int i = 0; i < 4; ++i) { accl[0][i] *= f0; accl[1][i] *= f1; }
      m0 = n0; m1 = n1;
    }

#pragma unroll
    for (int g = 0; g < 2; ++g) {
      const float mm = g ? m1 : m0;
#pragma unroll
      for (int t = 0; t < 4; ++t) {
        uint2 pw;
        pw.x = cvtpk(ex2(st[g][t][0] - mm), ex2(st[g][t][1] - mm));
        pw.y = cvtpk(ex2(st[g][t][2] - mm), ex2(st[g][t][3] - mm));
        *(uint2*)&Pw[(g * 16 + lq) * 72 + 16 * t + 4 * hi] = pw;
      }
    }

    b16x8 av0[4], av1[4];
#pragma unroll
    for (int t = 0; t < 4; ++t) {
      const int rv = 16 * t + lq;
      av0[t] = *(const b16x8*)&Vl[rv * 64 + ((hi ^ key) << 3)];
      av1[t] = *(const b16x8*)&Vl[rv * 64 + (((4 + hi) ^ key) << 3)];
    }

#pragma unroll
    for (int g = 0; g < 2; ++g) {
      b16x8 bp0 = *(const b16x8*)&Pw[(g * 16 + lq) * 72 + hi * 8];
      b16x8 bp1 = *(const b16x8*)&Pw[(g * 16 + lq) * 72 + 32 + hi * 8];
      accl[g] = mfma16(ones, bp0, accl[g]);
      accl[g] = mfma16(ones, bp1, accl[g]);
#pragma unroll
      for (int t = 0; t < 4; ++t) {
        acc[g][t] = mfma16(av0[t], bp0, acc[g][t]);
        acc[g][t] = mfma16(av1[t], bp1, acc[g][t]);
      }
    }
  }

#pragma unroll
  for (int g = 0; g < 2; ++g) {
    const float inv = 1.0f / accl[g][0];
    const size_t ob = (rowb + qw0 + g * 16 + lq) * (size_t)sO + h * 64;
#pragma unroll
    for (int t = 0; t < 4; ++t) {
      const int d = 16 * t + 4 * hi;
      if constexpr (sizeof(OT) == 2) {
        b16x4 o;
        o[0] = (short)f2bf(acc[g][t][0] * inv);
        o[1] = (short)f2bf(acc[g][t][1] * inv);
        o[2] = (short)f2bf(acc[g][t][2] * inv);
        o[3] = (short)f2bf(acc[g][t][3] * inv);
        *(b16x4*)&((u16*)Op)[ob + d] = o;
      } else {
        float4 o = make_float4(acc[g][t][0] * inv, acc[g][t][1] * inv,
                               acc[g][t][2] * inv, acc[g][t][3] * inv);
        *(float4*)&((float*)Op)[ob + d] = o;
      }
    }
  }
}

extern "C" void kernel_launch(void* const* d_in, const int* in_sizes, int n_in,
                              void* d_out, int out_size, void* d_ws, size_t ws_size,
                              hipStream_t stream) {
  (void)in_sizes; (void)n_in; (void)out_size; (void)ws_size;
  const float* x   = (const float*)d_in[0];
  const float* enc = (const float*)d_in[1];
  const float* wqs = (const float*)d_in[4];
  const float* wks = (const float*)d_in[5];
  const float* wvs = (const float*)d_in[6];
  const float* wqc = (const float*)d_in[7];
  const float* wkc = (const float*)d_in[8];
  const float* wvc = (const float*)d_in[9];

  u16* ws   = (u16*)d_ws;
  u16* xb   = ws;                  // 4096x1024 A of QKV1; then V1^T
  u16* encb = ws + 4194304;        // 4096x1024 A of KV2 ; then V2^T
  u16* wsc  = ws + 8388608;        // 3x 1024x1024
  u16* wcc  = ws + 11534336;       // 3x 1024x1024
  u16* qkv1 = ws + 14680064;       // 4096x3072
  u16* x1b  = ws + 27262976;       // 4096x1024 attn1 out
  u16* q2   = ws + 31457280;       // 4096x1024 Q2 out
  u16* kv2  = ws + 35651584;       // 4096x2048

  k_cvt_all<<<7168, 256, 0, stream>>>(x, enc, wqs, wks, wvs, wqc, wkc, wvc,
                                      xb, encb, wsc, wcc);

  // QKV1 (bx<24) + KV2 (bx>=24) fused: KV2 independent of attention layer 1.
  k_gemm_bt<<<dim3(40, 32), 256, 0, stream>>>(xb, wsc, qkv1, 3072, 24,
                                              encb, wcc + 1048576, kv2, 2048);

  // both V transposes: V1 from qkv1 -> xb ; V2 from kv2 -> encb
  k_vt2x<<<dim3(16, 128), 256, 0, stream>>>(qkv1, 3072, 2048, xb,
                                            kv2, 2048, 1024, encb);

  attn4<1, u16><<<dim3(8, 64), 256, 0, stream>>>(
      qkv1, 3072, qkv1, 3072, 1024, xb, x1b, 1024);

  // layer 2: Q2 projection (single problem; both sets identical)
  k_gemm_bt<<<dim3(8, 32), 256, 0, stream>>>(x1b, wcc, q2, 1024, 8,
                                             x1b, wcc, q2, 1024);

  attn4<0, float><<<dim3(8, 64), 256, 0, stream>>>(
      q2, 1024, kv2, 2048, 0, encb, (float*)d_out, 1024);
}

// Round 9
// 252.159 us; speedup vs baseline: 1.1111x; 1.0245x over previous
//
#include <hip/hip_runtime.h>
#include <stdint.h>

// R9: R8 + chunked XCD swizzle on the fused GEMM (10bx x 16by chunks, 4x2
// chunk grid) so each XCD's B-panel set (2.5 MB) stays L2-resident.
// Everything else byte-identical to R8 (GEMM body R5-pinned, attn4 R5-pinned).
// B=4 S=1024 D=1024 H=16 DK=64.

typedef unsigned short u16;
typedef short b16x8 __attribute__((ext_vector_type(8)));
typedef short b16x4 __attribute__((ext_vector_type(4)));
typedef float f32x4 __attribute__((ext_vector_type(4)));

__device__ __forceinline__ u16 f2bf(float f) {
  union { float f; uint32_t u; } v; v.f = f;
  uint32_t r = v.u + 0x7fffu + ((v.u >> 16) & 1u);
  return (u16)(r >> 16);
}

__device__ __forceinline__ f32x4 mfma16(b16x8 a, b16x8 b, f32x4 c) {
  return __builtin_amdgcn_mfma_f32_16x16x32_bf16(a, b, c, 0, 0, 0);
}

__device__ __forceinline__ void gld16(const void* g, void* l) {
  __builtin_amdgcn_global_load_lds(
      (const __attribute__((address_space(1))) void*)g,
      (__attribute__((address_space(3))) void*)l, 16, 0, 0);
}

__device__ __forceinline__ float ex2(float x) {
  float r; asm("v_exp_f32 %0, %1" : "=v"(r) : "v"(x)); return r;
}

__device__ __forceinline__ uint32_t cvtpk(float a, float b) {
  uint32_t r;
  asm("v_cvt_pk_bf16_f32 %0, %1, %2" : "=v"(r) : "v"(a), "v"(b));
  return r;
}

// ---------------- fused f32 -> bf16 convert (x, enc, 6 weights) ----------
__global__ __launch_bounds__(256) void k_cvt_all(
    const float* __restrict__ x, const float* __restrict__ enc,
    const float* __restrict__ w0, const float* __restrict__ w1,
    const float* __restrict__ w2, const float* __restrict__ w3,
    const float* __restrict__ w4, const float* __restrict__ w5,
    u16* __restrict__ xb, u16* __restrict__ encb,
    u16* __restrict__ wsc, u16* __restrict__ wcc) {
  const int id = blockIdx.x;
  const float* in;
  u16* out;
  float sc = 1.0f;
  int off;
  if (id < 2048) {
    in = x; out = xb; off = id;
  } else if (id < 4096) {
    in = enc; out = encb; off = id - 2048;
  } else {
    const int wi = (id - 4096) >> 9;
    off = (id - 4096) & 511;
    switch (wi) {
      case 0: in = w0; break; case 1: in = w1; break; case 2: in = w2; break;
      case 3: in = w3; break; case 4: in = w4; break; default: in = w5; break;
    }
    out = (wi < 3 ? wsc : wcc) + (wi % 3) * 1048576;
    if (wi % 3 == 0) sc = 0.18033688f;  // 0.125 * log2(e) folded into wq
  }
  const int i = (off * 256 + threadIdx.x) * 8;
  float4 a = *(const float4*)(in + i);
  float4 b = *(const float4*)(in + i + 4);
  b16x8 v;
  v[0] = (short)f2bf(a.x * sc); v[1] = (short)f2bf(a.y * sc);
  v[2] = (short)f2bf(a.z * sc); v[3] = (short)f2bf(a.w * sc);
  v[4] = (short)f2bf(b.x * sc); v[5] = (short)f2bf(b.y * sc);
  v[6] = (short)f2bf(b.z * sc); v[7] = (short)f2bf(b.w * sc);
  *(b16x8*)(out + i) = v;
}

// -------- bf16 GEMM: C[M,N] = A[M,K].B[N,K]^T  (R5-pinned body+epilogue) --
// M=4096, K=1024 fixed; 128x128 tile, BK=32. Dual-problem mux: bx < nbx0 ->
// set0, else set1. CHUNKED=1: grid (40,32), 8 XCD chunks of 10bx x 16by
// (bx-inner traversal keeps the 2.5 MB B-panel set L2-resident per XCD).
template <int CHUNKED>
__global__ __launch_bounds__(256) void k_gemm_bt(
    const u16* __restrict__ A0, const u16* __restrict__ B0,
    u16* __restrict__ C0, int N0, int nbx0,
    const u16* __restrict__ A1, const u16* __restrict__ B1,
    u16* __restrict__ C1, int N1) {
  __shared__ u16 Ab[128 * 32];
  __shared__ u16 Bb[128 * 32];
  const int tid = threadIdx.x;
  const int lane = tid & 63, w = tid >> 6;
  const int wr = w >> 1, wc = w & 1;
  const int q = lane & 15, hi = lane >> 4;
  const int id = blockIdx.y * gridDim.x + blockIdx.x;
  int bx, by;
  if (CHUNKED) {
    // 8 chunks (4 in bx, 2 in by), each 10 bx x 16 by = 160 tiles.
    const int xcd = id & 7, i = id >> 3;
    bx = (xcd & 3) * 10 + (i % 10);
    by = (xcd >> 2) * 16 + (i / 10);
  } else {
    const int nwg = gridDim.x * gridDim.y;
    const int swz = (id & 7) * (nwg >> 3) + (id >> 3);  // bijective (nwg%8==0)
    bx = swz % gridDim.x;
    by = swz / gridDim.x;
  }
  const u16* A; const u16* B; u16* C; int N, nb;
  if (bx < nbx0) { A = A0; B = B0; C = C0; N = N0; nb = bx; }
  else           { A = A1; B = B1; C = C1; N = N1; nb = bx - nbx0; }
  const int mbase = by * 128, nbase = nb * 128;
  f32x4 acc[4][4] = {};
  for (int kb = 0; kb < 1024; kb += 32) {
    __syncthreads();
#pragma unroll
    for (int r = 0; r < 2; ++r) {
      int c = tid + 256 * r;
      int row = c >> 2, ch = c & 3;
      gld16(&A[(size_t)(mbase + row) * 1024 + kb + ch * 8], &Ab[c * 8]);
      gld16(&B[(size_t)(nbase + row) * 1024 + kb + ch * 8], &Bb[c * 8]);
    }
    __syncthreads();
    b16x8 af[4], bf[4];
#pragma unroll
    for (int mi = 0; mi < 4; ++mi)
      af[mi] = *(const b16x8*)&Ab[(wr * 64 + mi * 16 + q) * 32 + hi * 8];
#pragma unroll
    for (int ni = 0; ni < 4; ++ni)
      bf[ni] = *(const b16x8*)&Bb[(wc * 64 + ni * 16 + q) * 32 + hi * 8];
#pragma unroll
    for (int mi = 0; mi < 4; ++mi)
#pragma unroll
      for (int ni = 0; ni < 4; ++ni)
        acc[mi][ni] = mfma16(af[mi], bf[ni], acc[mi][ni]);
  }
#pragma unroll
  for (int mi = 0; mi < 4; ++mi)
#pragma unroll
    for (int ni = 0; ni < 4; ++ni) {
      int m0 = mbase + wr * 64 + mi * 16 + hi * 4;
      int n0 = nbase + wc * 64 + ni * 16 + q;
#pragma unroll
      for (int i = 0; i < 4; ++i)
        C[(size_t)(m0 + i) * N + n0] = f2bf(acc[mi][ni][i]);
    }
}

// ---- fused V transposes: sel=blockIdx.y>>6 picks (in,stride,coff,out) ----
// in[b*1024+k][coff+h*64+d] -> out[bh][d][k]
__global__ __launch_bounds__(256) void k_vt2x(
    const u16* __restrict__ in0, int s0, int c0, u16* __restrict__ out0,
    const u16* __restrict__ in1, int s1, int c1, u16* __restrict__ out1) {
  __shared__ u16 T[64 * 72];
  const int tid = threadIdx.x;
  const int sel = blockIdx.y >> 6;
  const u16* in = sel ? in1 : in0;
  u16* out = sel ? out1 : out0;
  const int sIn = sel ? s1 : s0, coff = sel ? c1 : c0;
  const int bh = blockIdx.y & 63, kb = blockIdx.x * 64;
  const int b = bh >> 4, h = bh & 15;
  const int kvp = tid >> 3, ch = tid & 7;
  const u16* p = in + (size_t)(b * 1024 + kb + 2 * kvp) * sIn + coff + h * 64 + ch * 8;
  b16x8 r0 = *(const b16x8*)p;
  b16x8 r1 = *(const b16x8*)(p + sIn);
#pragma unroll
  for (int j = 0; j < 8; ++j) {
    int i = (j + ch) & 7;
    uint32_t pk = (uint32_t)(u16)r0[i] | ((uint32_t)(u16)r1[i] << 16);
    *(uint32_t*)&T[(ch * 8 + i) * 72 + 2 * kvp] = pk;
  }
  __syncthreads();
  const int d = tid >> 2, seg = tid & 3;
  b16x8 v0 = *(const b16x8*)&T[d * 72 + seg * 16];
  b16x8 v1 = *(const b16x8*)&T[d * 72 + seg * 16 + 8];
  u16* o = out + (size_t)(bh * 64 + d) * 1024 + kb + seg * 16;
  *(b16x8*)o = v0;
  *(b16x8*)(o + 8) = v1;
}

// ---------------- flash attention, 4-wave LDS-staged (R5-verified) --------
template <int CAUSAL, typename OT>
__global__ __launch_bounds__(256, 3) void attn4(
    const u16* __restrict__ Qp, int sQ,
    const u16* __restrict__ Kp, int sK, int koff,
    const u16* __restrict__ Vt,  // [bh][64 d][1024 kv]
    OT* __restrict__ Op, int sO) {
  __shared__ u16 Ksh[2][64 * 64];
  __shared__ u16 Vsh[2][64 * 64];
  __shared__ u16 Plds[4][32 * 72];
  const int tid = threadIdx.x;
  const int lane = tid & 63, w = tid >> 6;
  const int lq = lane & 15, hi = lane >> 4;

  const int id = blockIdx.y * gridDim.x + blockIdx.x;  // grid (8, 64)
  const int xcd = id & 7, l = id >> 3;
  const int bh = xcd * 8 + (l >> 3);
  const int qb = (l < 32) ? (l & 7) : 7 - (l & 7);

  const size_t rowb = (size_t)(bh >> 4) * 1024;
  const int h = bh & 15;
  const int qw0 = qb * 128 + w * 32;
  const int nt = CAUSAL ? 2 * qb + 2 : 16;

  const u16* Kbase = Kp + rowb * (size_t)sK + koff + h * 64;
  const u16* Vbase = Vt + (size_t)bh * 65536;
  const u16* Qb = Qp + (rowb + qw0 + lq) * (size_t)sQ + h * 64 + hi * 8;
  u16* Pw = &Plds[w][0];

  b16x8 qf[2][2];
  qf[0][0] = *(const b16x8*)Qb;
  qf[0][1] = *(const b16x8*)(Qb + 32);
  qf[1][0] = *(const b16x8*)(Qb + (size_t)16 * sQ);
  qf[1][1] = *(const b16x8*)(Qb + (size_t)16 * sQ + 32);

  b16x8 ones;
#pragma unroll
  for (int i = 0; i < 8; ++i) ones[i] = (short)0x3F80;

  const int key = lq & 7;

  f32x4 acc[2][4] = {};
  f32x4 accl[2] = {};
  float m0 = -1e30f, m1 = -1e30f;

  auto stage = [&](int bf, int kt2) {
    const int kb2 = kt2 * 64;
#pragma unroll
    for (int r = 0; r < 2; ++r) {
      int c = tid + 256 * r;
      int row = c >> 3, ch = c & 7;
      int sw = row & 7;
      gld16(&Kbase[(size_t)(kb2 + row) * sK + ((ch ^ sw) << 3)],
            &Ksh[bf][c * 8]);
      gld16(&Vbase[(size_t)row * 1024 + kb2 + ((ch ^ sw) << 3)],
            &Vsh[bf][c * 8]);
    }
  };

  stage(0, 0);
  for (int kt = 0; kt < nt; ++kt) {
    __syncthreads();
    if (kt + 1 < nt) stage((kt + 1) & 1, kt + 1);
    const int kb = kt * 64;
    if (CAUSAL && kb > qw0 + 31) continue;
    const u16* Kl = Ksh[kt & 1];
    const u16* Vl = Vsh[kt & 1];

    f32x4 st[2][4];
#pragma unroll
    for (int t = 0; t < 4; ++t) {
      const int row = 16 * t + lq;
      b16x8 k0 = *(const b16x8*)&Kl[row * 64 + ((hi ^ key) << 3)];
      b16x8 k1 = *(const b16x8*)&Kl[row * 64 + (((4 + hi) ^ key) << 3)];
      f32x4 z0 = {}, z1 = {};
      z0 = mfma16(k0, qf[0][0], z0);
      st[0][t] = mfma16(k1, qf[0][1], z0);
      z1 = mfma16(k0, qf[1][0], z1);
      st[1][t] = mfma16(k1, qf[1][1], z1);
    }

    const bool dm = CAUSAL && (kb + 63 > qw0);
    float pm[2];
#pragma unroll
    for (int g = 0; g < 2; ++g) {
      if (dm) {
        const int qg = qw0 + g * 16 + lq;
#pragma unroll
        for (int t = 0; t < 4; ++t)
#pragma unroll
          for (int i = 0; i < 4; ++i)
            if (kb + 16 * t + 4 * hi + i > qg) st[g][t][i] = -INFINITY;
      }
      float m = -INFINITY;
#pragma unroll
      for (int t = 0; t < 4; ++t)
#pragma unroll
        for (int i = 0; i < 4; ++i) m = fmaxf(m, st[g][t][i]);
      m = fmaxf(m, __shfl_xor(m, 16));
      m = fmaxf(m, __shfl_xor(m, 32));
      pm[g] = m;
    }

    if (!__all((pm[0] <= m0 + 10.f) && (pm[1] <= m1 + 10.f))) {
      float n0 = fmaxf(m0, pm[0]), n1 = fmaxf(m1, pm[1]);
      float f0 = ex2(m0 - n0), f1 = ex2(m1 - n1);
#pragma unroll
      for (int t = 0; t < 4; ++t)
#pragma unroll
        for (int i = 0; i < 4; ++i) {
          acc[0][t][i] *= f0;
          acc[1][t][i] *= f1;
        }
#pragma unroll
      for (int i = 0; i < 4; ++i) { accl[0][i] *= f0; accl[1][i] *= f1; }
      m0 = n0; m1 = n1;
    }

#pragma unroll
    for (int g = 0; g < 2; ++g) {
      const float mm = g ? m1 : m0;
#pragma unroll
      for (int t = 0; t < 4; ++t) {
        uint2 pw;
        pw.x = cvtpk(ex2(st[g][t][0] - mm), ex2(st[g][t][1] - mm));
        pw.y = cvtpk(ex2(st[g][t][2] - mm), ex2(st[g][t][3] - mm));
        *(uint2*)&Pw[(g * 16 + lq) * 72 + 16 * t + 4 * hi] = pw;
      }
    }

    b16x8 av0[4], av1[4];
#pragma unroll
    for (int t = 0; t < 4; ++t) {
      const int rv = 16 * t + lq;
      av0[t] = *(const b16x8*)&Vl[rv * 64 + ((hi ^ key) << 3)];
      av1[t] = *(const b16x8*)&Vl[rv * 64 + (((4 + hi) ^ key) << 3)];
    }

#pragma unroll
    for (int g = 0; g < 2; ++g) {
      b16x8 bp0 = *(const b16x8*)&Pw[(g * 16 + lq) * 72 + hi * 8];
      b16x8 bp1 = *(const b16x8*)&Pw[(g * 16 + lq) * 72 + 32 + hi * 8];
      accl[g] = mfma16(ones, bp0, accl[g]);
      accl[g] = mfma16(ones, bp1, accl[g]);
#pragma unroll
      for (int t = 0; t < 4; ++t) {
        acc[g][t] = mfma16(av0[t], bp0, acc[g][t]);
        acc[g][t] = mfma16(av1[t], bp1, acc[g][t]);
      }
    }
  }

#pragma unroll
  for (int g = 0; g < 2; ++g) {
    const float inv = 1.0f / accl[g][0];
    const size_t ob = (rowb + qw0 + g * 16 + lq) * (size_t)sO + h * 64;
#pragma unroll
    for (int t = 0; t < 4; ++t) {
      const int d = 16 * t + 4 * hi;
      if constexpr (sizeof(OT) == 2) {
        b16x4 o;
        o[0] = (short)f2bf(acc[g][t][0] * inv);
        o[1] = (short)f2bf(acc[g][t][1] * inv);
        o[2] = (short)f2bf(acc[g][t][2] * inv);
        o[3] = (short)f2bf(acc[g][t][3] * inv);
        *(b16x4*)&((u16*)Op)[ob + d] = o;
      } else {
        float4 o = make_float4(acc[g][t][0] * inv, acc[g][t][1] * inv,
                               acc[g][t][2] * inv, acc[g][t][3] * inv);
        *(float4*)&((float*)Op)[ob + d] = o;
      }
    }
  }
}

extern "C" void kernel_launch(void* const* d_in, const int* in_sizes, int n_in,
                              void* d_out, int out_size, void* d_ws, size_t ws_size,
                              hipStream_t stream) {
  (void)in_sizes; (void)n_in; (void)out_size; (void)ws_size;
  const float* x   = (const float*)d_in[0];
  const float* enc = (const float*)d_in[1];
  const float* wqs = (const float*)d_in[4];
  const float* wks = (const float*)d_in[5];
  const float* wvs = (const float*)d_in[6];
  const float* wqc = (const float*)d_in[7];
  const float* wkc = (const float*)d_in[8];
  const float* wvc = (const float*)d_in[9];

  u16* ws   = (u16*)d_ws;
  u16* xb   = ws;                  // 4096x1024 A of QKV1; then V1^T
  u16* encb = ws + 4194304;        // 4096x1024 A of KV2 ; then V2^T
  u16* wsc  = ws + 8388608;        // 3x 1024x1024
  u16* wcc  = ws + 11534336;       // 3x 1024x1024
  u16* qkv1 = ws + 14680064;       // 4096x3072
  u16* x1b  = ws + 27262976;       // 4096x1024 attn1 out
  u16* q2   = ws + 31457280;       // 4096x1024 Q2 out
  u16* kv2  = ws + 35651584;       // 4096x2048

  k_cvt_all<<<7168, 256, 0, stream>>>(x, enc, wqs, wks, wvs, wqc, wkc, wvc,
                                      xb, encb, wsc, wcc);

  // QKV1 (bx<24) + KV2 (bx>=24) fused; chunked XCD swizzle (10x16 chunks).
  k_gemm_bt<1><<<dim3(40, 32), 256, 0, stream>>>(xb, wsc, qkv1, 3072, 24,
                                                 encb, wcc + 1048576, kv2, 2048);

  // both V transposes: V1 from qkv1 -> xb ; V2 from kv2 -> encb
  k_vt2x<<<dim3(16, 128), 256, 0, stream>>>(qkv1, 3072, 2048, xb,
                                            kv2, 2048, 1024, encb);

  attn4<1, u16><<<dim3(8, 64), 256, 0, stream>>>(
      qkv1, 3072, qkv1, 3072, 1024, xb, x1b, 1024);

  // layer 2: Q2 projection (single problem; both sets identical)
  k_gemm_bt<0><<<dim3(8, 32), 256, 0, stream>>>(x1b, wcc, q2, 1024, 8,
                                                x1b, wcc, q2, 1024);

  attn4<0, float><<<dim3(8, 64), 256, 0, stream>>>(
      q2, 1024, kv2, 2048, 0, encb, (float*)d_out, 1024);
}